// Round 7
// baseline (369.313 us; speedup 1.0000x reference)
//
#include <hip/hip_runtime.h>
#include <hip/hip_bf16.h>

#define BB 2
#define HH 12
#define SS 4096
#define DD 768
#define HD 64
#define NBK 64
#define MC 3

typedef __attribute__((ext_vector_type(8))) short short8_t;
typedef __attribute__((ext_vector_type(4))) float float4_t;

__device__ __forceinline__ unsigned short f2bf(float f) {
  union { float f; unsigned u; } c;
  c.f = f;
  unsigned u = c.u + 0x7FFFu + ((c.u >> 16) & 1u);  // RNE
  return (unsigned short)(u >> 16);
}

#define LDK 72  // LDS row stride in shorts (144B): 2-way-free fragment reads

// ---------------------------------------------------------------------------
// One-shot fp32 -> bf16 conversion: hs (8192x768), Wq|Wk|Wv packed (2304x768),
// Wo (768x768). One float4 per thread.
// ---------------------------------------------------------------------------
__global__ __launch_bounds__(256) void cvt_all(
    const float* __restrict__ hs, const float* __restrict__ Wq,
    const float* __restrict__ Wk, const float* __restrict__ Wv,
    const float* __restrict__ Wo, unsigned short* __restrict__ hsb,
    unsigned short* __restrict__ wqkvb, unsigned short* __restrict__ wob) {
  long i4 = (long)blockIdx.x * 256 + threadIdx.x;  // float4 index
  const float* src;
  unsigned short* dst;
  if (i4 < 1572864) {          // hs: 6291456 floats
    src = hs + i4 * 4;
    dst = hsb + i4 * 4;
  } else {
    long r = i4 - 1572864;
    int w = (int)(r / 147456);  // 0..3 : Wq,Wk,Wv,Wo (589824 floats each)
    long e = r % 147456;
    src = (w == 0 ? Wq : w == 1 ? Wk : w == 2 ? Wv : Wo) + e * 4;
    dst = (w < 3) ? (wqkvb + (long)w * 589824 + e * 4) : (wob + e * 4);
  }
  float4_t v = *(const float4_t*)src;
  uint2 p;
  p.x = (unsigned)f2bf(v[0]) | ((unsigned)f2bf(v[1]) << 16);
  p.y = (unsigned)f2bf(v[2]) | ((unsigned)f2bf(v[3]) << 16);
  *(uint2*)dst = p;
}

// ---------------------------------------------------------------------------
// QKV projection, bf16 inputs, register-double-buffered staging.
// A [8192][768], W packed [2304][768]. Two threads per 64-short row; each
// thread moves 4 consecutive uint4 (32 shorts) per matrix per K-tile.
// Q: [b][h][s][d] scaled 0.125; K: [b][h][s][d]; V: transposed [b][h][d][s].
// ---------------------------------------------------------------------------
__global__ __launch_bounds__(256) void gemm_qkv_b(
    const unsigned short* __restrict__ A, const unsigned short* __restrict__ W,
    unsigned short* __restrict__ qb, unsigned short* __restrict__ kb,
    unsigned short* __restrict__ vtb) {
  __shared__ unsigned short As[128 * LDK];
  __shared__ unsigned short Bs[128 * LDK];
  int tid = threadIdx.x;
  int m0 = blockIdx.x * 128;
  int n0 = blockIdx.y * 128;  // 0..2176
  int lane = tid & 63;
  int w = tid >> 6;
  int wm = (w >> 1) * 64;
  int wn = (w & 1) * 64;

  int sr = tid >> 1;           // row 0..127
  int sc0 = (tid & 1) * 32;    // shorts 0 or 32; 4 uint4 = 32 shorts each

  float4_t acc[4][4];
#pragma unroll
  for (int i = 0; i < 4; i++)
#pragma unroll
    for (int j = 0; j < 4; j++)
#pragma unroll
      for (int r = 0; r < 4; r++) acc[i][j][r] = 0.f;

  uint4 pa[4], pb[4];
  {
    const unsigned short* ap = A + (size_t)(m0 + sr) * DD + sc0;
    const unsigned short* wp = W + (size_t)(n0 + sr) * DD + sc0;
#pragma unroll
    for (int i = 0; i < 4; i++) {
      pa[i] = *(const uint4*)(ap + 8 * i);
      pb[i] = *(const uint4*)(wp + 8 * i);
    }
  }

  for (int kt = 0; kt < DD; kt += 64) {
    __syncthreads();  // previous compute done reading LDS
#pragma unroll
    for (int i = 0; i < 4; i++) {
      *(uint4*)&As[sr * LDK + sc0 + 8 * i] = pa[i];
      *(uint4*)&Bs[sr * LDK + sc0 + 8 * i] = pb[i];
    }
    __syncthreads();
    if (kt + 64 < DD) {  // prefetch next K-tile; hides behind MFMA compute
      const unsigned short* ap = A + (size_t)(m0 + sr) * DD + kt + 64 + sc0;
      const unsigned short* wp = W + (size_t)(n0 + sr) * DD + kt + 64 + sc0;
#pragma unroll
      for (int i = 0; i < 4; i++) {
        pa[i] = *(const uint4*)(ap + 8 * i);
        pb[i] = *(const uint4*)(wp + 8 * i);
      }
    }
#pragma unroll
    for (int kk = 0; kk < 64; kk += 32) {
      int fr = lane & 15;
      int fk = ((lane >> 4) << 3) + kk;
      short8_t af[4], bfr[4];
#pragma unroll
      for (int i = 0; i < 4; i++)
        af[i] = *(const short8_t*)&As[(wm + i * 16 + fr) * LDK + fk];
#pragma unroll
      for (int j = 0; j < 4; j++)
        bfr[j] = *(const short8_t*)&Bs[(wn + j * 16 + fr) * LDK + fk];
#pragma unroll
      for (int i = 0; i < 4; i++)
#pragma unroll
        for (int j = 0; j < 4; j++)
          acc[i][j] = __builtin_amdgcn_mfma_f32_16x16x32_bf16(
              af[i], bfr[j], acc[i][j], 0, 0, 0);
    }
  }

  int cn = lane & 15;
  int rb = (lane >> 4) * 4;
  int ysel = n0 / 768;                        // tile never straddles (768%128==0)
  float scale = (ysel == 0) ? 0.125f : 1.0f;  // fold 1/sqrt(64) into Q
#pragma unroll
  for (int i = 0; i < 4; i++)
#pragma unroll
    for (int j = 0; j < 4; j++)
#pragma unroll
      for (int r = 0; r < 4; r++) {
        int m = m0 + wm + i * 16 + rb + r;
        int n = n0 + wn + j * 16 + cn;
        unsigned short hv = f2bf(acc[i][j][r] * scale);
        int b = m >> 12, s = m & 4095;
        int nn = n - ysel * 768;
        int h = nn >> 6, d = nn & 63;
        if (ysel == 0)
          qb[(((size_t)b * HH + h) * SS + s) * HD + d] = hv;
        else if (ysel == 1)
          kb[(((size_t)b * HH + h) * SS + s) * HD + d] = hv;
        else
          vtb[(((size_t)b * HH + h) * HD + d) * SS + s] = hv;
      }
}

// ---------------------------------------------------------------------------
// Output projection, bf16 inputs, fp32 output, register-double-buffered.
// ---------------------------------------------------------------------------
__global__ __launch_bounds__(256) void gemm_out_b(
    const unsigned short* __restrict__ A, const unsigned short* __restrict__ W,
    float* __restrict__ dst) {
  __shared__ unsigned short As[128 * LDK];
  __shared__ unsigned short Bs[128 * LDK];
  int tid = threadIdx.x;
  int m0 = blockIdx.x * 128;
  int n0 = blockIdx.y * 128;
  int lane = tid & 63;
  int w = tid >> 6;
  int wm = (w >> 1) * 64;
  int wn = (w & 1) * 64;

  int sr = tid >> 1;
  int sc0 = (tid & 1) * 32;

  float4_t acc[4][4];
#pragma unroll
  for (int i = 0; i < 4; i++)
#pragma unroll
    for (int j = 0; j < 4; j++)
#pragma unroll
      for (int r = 0; r < 4; r++) acc[i][j][r] = 0.f;

  uint4 pa[4], pb[4];
  {
    const unsigned short* ap = A + (size_t)(m0 + sr) * DD + sc0;
    const unsigned short* wp = W + (size_t)(n0 + sr) * DD + sc0;
#pragma unroll
    for (int i = 0; i < 4; i++) {
      pa[i] = *(const uint4*)(ap + 8 * i);
      pb[i] = *(const uint4*)(wp + 8 * i);
    }
  }

  for (int kt = 0; kt < DD; kt += 64) {
    __syncthreads();
#pragma unroll
    for (int i = 0; i < 4; i++) {
      *(uint4*)&As[sr * LDK + sc0 + 8 * i] = pa[i];
      *(uint4*)&Bs[sr * LDK + sc0 + 8 * i] = pb[i];
    }
    __syncthreads();
    if (kt + 64 < DD) {
      const unsigned short* ap = A + (size_t)(m0 + sr) * DD + kt + 64 + sc0;
      const unsigned short* wp = W + (size_t)(n0 + sr) * DD + kt + 64 + sc0;
#pragma unroll
      for (int i = 0; i < 4; i++) {
        pa[i] = *(const uint4*)(ap + 8 * i);
        pb[i] = *(const uint4*)(wp + 8 * i);
      }
    }
#pragma unroll
    for (int kk = 0; kk < 64; kk += 32) {
      int fr = lane & 15;
      int fk = ((lane >> 4) << 3) + kk;
      short8_t af[4], bfr[4];
#pragma unroll
      for (int i = 0; i < 4; i++)
        af[i] = *(const short8_t*)&As[(wm + i * 16 + fr) * LDK + fk];
#pragma unroll
      for (int j = 0; j < 4; j++)
        bfr[j] = *(const short8_t*)&Bs[(wn + j * 16 + fr) * LDK + fk];
#pragma unroll
      for (int i = 0; i < 4; i++)
#pragma unroll
        for (int j = 0; j < 4; j++)
          acc[i][j] = __builtin_amdgcn_mfma_f32_16x16x32_bf16(
              af[i], bfr[j], acc[i][j], 0, 0, 0);
    }
  }

  int cn = lane & 15;
  int rb = (lane >> 4) * 4;
#pragma unroll
  for (int i = 0; i < 4; i++)
#pragma unroll
    for (int j = 0; j < 4; j++)
#pragma unroll
      for (int r = 0; r < 4; r++) {
        int m = m0 + wm + i * 16 + rb + r;
        int n = n0 + wn + j * 16 + cn;
        dst[(size_t)m * DD + n] = acc[i][j][r];
      }
}

// ---------------------------------------------------------------------------
// Block-sparse attention, fixed-max softmax (scores |s| <~ 2, exp-safe, and
// partials combine linearly). Heavy blocks (l=0,63) split 8 ways; each chunk
// writes unnormalized partial O + rowsum to scratch. Lights write bf16 ctx.
// Grid: ids 0..383 heavy chunks, 384..1871 lights.
// ---------------------------------------------------------------------------
__global__ __launch_bounds__(256) void attn2(
    const unsigned short* __restrict__ q, const unsigned short* __restrict__ k,
    const unsigned short* __restrict__ vt, const int* __restrict__ graph,
    unsigned short* __restrict__ ctxb, float* __restrict__ part) {
  __shared__ unsigned short Ks[64 * LDK];      // K[key][d]
  __shared__ unsigned short Vs[64 * LDK];      // V^T[d][key]
  __shared__ unsigned short Ps[4][16 * LDK];   // per-wave P[q][key]

  int tid = threadIdx.x;
  int id = blockIdx.x;
  int b, h, l, nkb, heavy, chunk = 0, hid = 0;
  int list[8];
  if (id < 384) {
    heavy = 1;
    hid = id >> 3;
    chunk = id & 7;
    b = hid / 24;
    int r = hid % 24;
    h = r >> 1;
    l = (r & 1) ? (NBK - 1) : 0;
    nkb = 8;
#pragma unroll
    for (int i = 0; i < 8; i++) list[i] = chunk * 8 + i;
  } else {
    heavy = 0;
    int j = id - 384;
    b = j / 744;  // 744 = 12*62
    int r = j % 744;
    h = r / 62;
    l = 1 + r % 62;
    const int* g = graph + (((size_t)b * HH + h) * NBK + l) * MC;
    int n = 0;
    if (l == 1) {
      list[0] = 0; list[1] = 1; list[2] = 2; list[3] = NBK - 1; n = 4;
    } else if (l == NBK - 2) {
      list[0] = 0; list[1] = NBK - 3; list[2] = NBK - 2; list[3] = NBK - 1; n = 4;
    } else {
      list[0] = 0; list[1] = l - 1; list[2] = l; list[3] = l + 1;
      list[4] = NBK - 1; n = 5;
    }
    for (int m = 0; m < MC; m++) list[n++] = g[m];
    nkb = n;
  }
  size_t base = ((size_t)b * HH + h) * SS * HD;

  int lane = tid & 63;
  int w = tid >> 6;
  int lr = lane & 15;     // fragment m/n index
  int quad = lane >> 4;   // fragment k-group

  // Q fragments (A-layout) straight from global into registers (q pre-scaled).
  short8_t qa[2];
  {
    const unsigned short* qp =
        q + base + (size_t)(l * 64 + w * 16 + lr) * HD + quad * 8;
    qa[0] = *(const short8_t*)qp;
    qa[1] = *(const short8_t*)(qp + 32);
  }

  float4_t Ot[4];
  float ls[4];  // per-lane partial row sums (4 cols/row this lane)
#pragma unroll
  for (int t = 0; t < 4; t++)
#pragma unroll
    for (int r = 0; r < 4; r++) Ot[t][r] = 0.f;
#pragma unroll
  for (int r = 0; r < 4; r++) ls[r] = 0.f;

  // staging: each thread moves 2x16B for K and 2x16B for Vt
  int srow = tid >> 3;          // 0..31
  int scol = (tid & 7) * 8;     // 0..56

  uint4 kr0, kr1, vr0, vr1;
  {
    int kb = list[0];
    const unsigned short* kp = k + base + (size_t)(kb * 64 + srow) * HD + scol;
    const unsigned short* vp = vt + base + (size_t)srow * SS + kb * 64 + scol;
    kr0 = *(const uint4*)kp;
    kr1 = *(const uint4*)(kp + 32 * HD);
    vr0 = *(const uint4*)vp;
    vr1 = *(const uint4*)(vp + 32 * SS);
  }

  for (int t = 0; t < nkb; t++) {
    *(uint4*)&Ks[srow * LDK + scol] = kr0;
    *(uint4*)&Ks[(srow + 32) * LDK + scol] = kr1;
    *(uint4*)&Vs[srow * LDK + scol] = vr0;
    *(uint4*)&Vs[(srow + 32) * LDK + scol] = vr1;
    __syncthreads();

    if (t + 1 < nkb) {  // prefetch next; hides behind compute
      int kb = list[t + 1];
      const unsigned short* kp = k + base + (size_t)(kb * 64 + srow) * HD + scol;
      const unsigned short* vp = vt + base + (size_t)srow * SS + kb * 64 + scol;
      kr0 = *(const uint4*)kp;
      kr1 = *(const uint4*)(kp + 32 * HD);
      vr0 = *(const uint4*)vp;
      vr1 = *(const uint4*)(vp + 32 * SS);
    }

    // S = Q K^T
    float4_t st[4];
#pragma unroll
    for (int tt = 0; tt < 4; tt++) {
#pragma unroll
      for (int r = 0; r < 4; r++) st[tt][r] = 0.f;
      short8_t kb0 = *(const short8_t*)&Ks[(tt * 16 + lr) * LDK + quad * 8];
      short8_t kb1 = *(const short8_t*)&Ks[(tt * 16 + lr) * LDK + quad * 8 + 32];
      st[tt] = __builtin_amdgcn_mfma_f32_16x16x32_bf16(qa[0], kb0, st[tt], 0, 0, 0);
      st[tt] = __builtin_amdgcn_mfma_f32_16x16x32_bf16(qa[1], kb1, st[tt], 0, 0, 0);
    }

    // fixed-max softmax: p = exp(s); per-lane partial sums, no shuffles.
#pragma unroll
    for (int tt = 0; tt < 4; tt++)
#pragma unroll
      for (int r = 0; r < 4; r++) {
        float p = __expf(st[tt][r]);
        st[tt][r] = p;
        ls[r] += p;
        Ps[w][(quad * 4 + r) * LDK + tt * 16 + lr] = f2bf(p);
      }

    // O += P V
#pragma unroll
    for (int s = 0; s < 2; s++) {
      short8_t pa = *(const short8_t*)&Ps[w][lr * LDK + s * 32 + quad * 8];
#pragma unroll
      for (int tt = 0; tt < 4; tt++) {
        short8_t vb =
            *(const short8_t*)&Vs[(tt * 16 + lr) * LDK + s * 32 + quad * 8];
        Ot[tt] = __builtin_amdgcn_mfma_f32_16x16x32_bf16(pa, vb, Ot[tt], 0, 0, 0);
      }
    }
    __syncthreads();
  }

  // reduce row sums across the 16 lanes holding each row
#pragma unroll
  for (int r = 0; r < 4; r++)
#pragma unroll
    for (int off = 1; off < 16; off <<= 1) ls[r] += __shfl_xor(ls[r], off);

  if (!heavy) {
#pragma unroll
    for (int r = 0; r < 4; r++) {
      float inv = 1.f / ls[r];
      size_t row = (size_t)b * SS + (size_t)l * 64 + w * 16 + quad * 4 + r;
#pragma unroll
      for (int tt = 0; tt < 4; tt++)
        ctxb[row * DD + h * HD + tt * 16 + lr] = f2bf(Ot[tt][r] * inv);
    }
  } else {
    float* pb = part + ((size_t)hid * 8 + chunk) * 4160;  // 64*64 O + 64 lsum
#pragma unroll
    for (int r = 0; r < 4; r++) {
      int rowi = w * 16 + quad * 4 + r;
#pragma unroll
      for (int tt = 0; tt < 4; tt++)
        pb[rowi * 64 + tt * 16 + lr] = Ot[tt][r];
      if (lr == 0) pb[4096 + rowi] = ls[r];
    }
  }
}

// ---------------------------------------------------------------------------
// Combine the 8 partials of each heavy block, normalize, write bf16 ctx.
// ---------------------------------------------------------------------------
__global__ __launch_bounds__(256) void reduce_heavy(
    const float* __restrict__ part, unsigned short* __restrict__ ctxb) {
  __shared__ float lrow[64];
  int hid = blockIdx.x;
  int tid = threadIdx.x;
  int b = hid / 24;
  int r = hid % 24;
  int h = r >> 1;
  int l = (r & 1) ? (NBK - 1) : 0;
  const float* pb = part + (size_t)hid * 8 * 4160;
  if (tid < 64) {
    float s = 0.f;
#pragma unroll
    for (int c = 0; c < 8; c++) s += pb[c * 4160 + 4096 + tid];
    lrow[tid] = s;
  }
  __syncthreads();
#pragma unroll
  for (int e = tid; e < 4096; e += 256) {
    float o = 0.f;
#pragma unroll
    for (int c = 0; c < 8; c++) o += pb[c * 4160 + e];
    int rowi = e >> 6, col = e & 63;
    size_t row = (size_t)b * SS + (size_t)l * 64 + rowi;
    ctxb[row * DD + h * HD + col] = f2bf(o / lrow[rowi]);
  }
}

extern "C" void kernel_launch(void* const* d_in, const int* in_sizes, int n_in,
                              void* d_out, int out_size, void* d_ws,
                              size_t ws_size, hipStream_t stream) {
  const float* hs = (const float*)d_in[0];
  const float* Wq = (const float*)d_in[1];
  const float* Wk = (const float*)d_in[2];
  const float* Wv = (const float*)d_in[3];
  const float* Wo = (const float*)d_in[4];
  const int* graph = (const int*)d_in[10];

  const size_t NHS = (size_t)BB * SS * DD;  // 6291456
  unsigned short* hsb = (unsigned short*)d_ws;
  unsigned short* wqkvb = hsb + NHS;            // 3*768*768
  unsigned short* wob = wqkvb + 3 * 768 * 768;  // 768*768
  unsigned short* qb = wob + 768 * 768;
  unsigned short* kb = qb + NHS;
  unsigned short* vtb = kb + NHS;
  unsigned short* ctxb = vtb + NHS;
  float* part = (float*)(ctxb + NHS);  // 48*8*4160 floats

  cvt_all<<<8448, 256, 0, stream>>>(hs, Wq, Wk, Wv, Wo, hsb, wqkvb, wob);
  gemm_qkv_b<<<dim3(64, 18, 1), 256, 0, stream>>>(hsb, wqkvb, qb, kb, vtb);
  attn2<<<1872, 256, 0, stream>>>(qb, kb, vtb, graph, ctxb, part);
  reduce_heavy<<<48, 256, 0, stream>>>(part, ctxb);
  gemm_out_b<<<dim3(64, 6, 1), 256, 0, stream>>>(ctxb, wob, (float*)d_out);
}

// Round 8
// 225.497 us; speedup vs baseline: 1.6378x; 1.6378x over previous
//
#include <hip/hip_runtime.h>
#include <hip/hip_bf16.h>

#define BB 2
#define HH 12
#define SS 4096
#define DD 768
#define HD 64
#define NBK 64
#define MC 3

typedef __attribute__((ext_vector_type(8))) short short8_t;
typedef __attribute__((ext_vector_type(4))) float float4_t;

__device__ __forceinline__ unsigned short f2bf(float f) {
  union { float f; unsigned u; } c;
  c.f = f;
  unsigned u = c.u + 0x7FFFu + ((c.u >> 16) & 1u);  // RNE
  return (unsigned short)(u >> 16);
}

// async 16B global -> LDS (gfx950). LDS dest = wave-uniform base + lane*16.
__device__ __forceinline__ void gload16(const unsigned short* gp,
                                        unsigned short* lp) {
  __builtin_amdgcn_global_load_lds(
      (const __attribute__((address_space(1))) unsigned int*)gp,
      (__attribute__((address_space(3))) unsigned int*)lp, 16, 0, 0);
}

#define LDK 72  // padded stride (attn kernel only)

// ---------------------------------------------------------------------------
// One-shot fp32 -> bf16 conversion: hs (8192x768), Wq|Wk|Wv packed (2304x768),
// Wo (768x768). One float4 per thread.
// ---------------------------------------------------------------------------
__global__ __launch_bounds__(256) void cvt_all(
    const float* __restrict__ hs, const float* __restrict__ Wq,
    const float* __restrict__ Wk, const float* __restrict__ Wv,
    const float* __restrict__ Wo, unsigned short* __restrict__ hsb,
    unsigned short* __restrict__ wqkvb, unsigned short* __restrict__ wob) {
  long i4 = (long)blockIdx.x * 256 + threadIdx.x;  // float4 index
  const float* src;
  unsigned short* dst;
  if (i4 < 1572864) {          // hs: 6291456 floats
    src = hs + i4 * 4;
    dst = hsb + i4 * 4;
  } else {
    long r = i4 - 1572864;
    int w = (int)(r / 147456);  // 0..3 : Wq,Wk,Wv,Wo (589824 floats each)
    long e = r % 147456;
    src = (w == 0 ? Wq : w == 1 ? Wk : w == 2 ? Wv : Wo) + e * 4;
    dst = (w < 3) ? (wqkvb + (long)w * 589824 + e * 4) : (wob + e * 4);
  }
  float4_t v = *(const float4_t*)src;
  uint2 p;
  p.x = (unsigned)f2bf(v[0]) | ((unsigned)f2bf(v[1]) << 16);
  p.y = (unsigned)f2bf(v[2]) | ((unsigned)f2bf(v[3]) << 16);
  *(uint2*)dst = p;
}

// ---------------------------------------------------------------------------
// Shared GEMM K-loop body: m97-style async staging into XOR-swizzled LDS.
// LDS row r (128B = 8 chunks of 16B); global chunk c stored at slot c^(r&7).
// Staging: group g = w*4+u covers rows g*8..g*8+7; lane j loads global chunk
// (j&7)^(j>>3) of row g*8+(j>>3) -> HW writes LDS base(g*1024B)+j*16.
// Fragment read: slot = (quad + kk/8) ^ (fr&7).
// ---------------------------------------------------------------------------
#define GEMM_K_LOOP(A_, B_, m0_, n0_)                                         \
  for (int kt = 0; kt < DD; kt += 64) {                                       \
    __syncthreads();                                                          \
    {                                                                         \
      int rr = lane >> 3;                                                     \
      int cg = (lane & 7) ^ rr;                                               \
      _Pragma("unroll") for (int u = 0; u < 4; u++) {                         \
        int g = w * 4 + u;                                                    \
        const unsigned short* ap =                                            \
            A_ + (size_t)(m0_ + g * 8 + rr) * DD + kt + cg * 8;               \
        const unsigned short* bp =                                            \
            B_ + (size_t)(n0_ + g * 8 + rr) * DD + kt + cg * 8;               \
        gload16(ap, &As[g * 512]);                                            \
        gload16(bp, &Bs[g * 512]);                                            \
      }                                                                       \
    }                                                                         \
    __syncthreads();                                                          \
    _Pragma("unroll") for (int kk = 0; kk < 64; kk += 32) {                   \
      int fr = lane & 15;                                                     \
      int quad = lane >> 4;                                                   \
      int cb = quad + (kk >> 3);                                              \
      short8_t af[4], bfr[4];                                                 \
      _Pragma("unroll") for (int i = 0; i < 4; i++) {                         \
        int r = wm + i * 16 + fr;                                             \
        af[i] = *(const short8_t*)&As[r * 64 + (cb ^ (fr & 7)) * 8];          \
      }                                                                       \
      _Pragma("unroll") for (int j = 0; j < 4; j++) {                         \
        int r = wn + j * 16 + fr;                                             \
        bfr[j] = *(const short8_t*)&Bs[r * 64 + (cb ^ (fr & 7)) * 8];         \
      }                                                                       \
      _Pragma("unroll") for (int i = 0; i < 4; i++)                           \
          _Pragma("unroll") for (int j = 0; j < 4; j++) acc[i][j] =           \
          __builtin_amdgcn_mfma_f32_16x16x32_bf16(af[i], bfr[j], acc[i][j],   \
                                                  0, 0, 0);                   \
    }                                                                         \
  }

// ---------------------------------------------------------------------------
// QKV projection, bf16 inputs, global_load_lds staging.
// Q: [b][h][s][d] scaled 0.125; K: [b][h][s][d]; V: transposed [b][h][d][s].
// ---------------------------------------------------------------------------
__global__ __launch_bounds__(256) void gemm_qkv_b(
    const unsigned short* __restrict__ A, const unsigned short* __restrict__ W,
    unsigned short* __restrict__ qb, unsigned short* __restrict__ kb,
    unsigned short* __restrict__ vtb) {
  __shared__ unsigned short As[128 * 64];
  __shared__ unsigned short Bs[128 * 64];
  int tid = threadIdx.x;
  int m0 = blockIdx.x * 128;
  int n0 = blockIdx.y * 128;  // 0..2176
  int lane = tid & 63;
  int w = tid >> 6;
  int wm = (w >> 1) * 64;
  int wn = (w & 1) * 64;

  float4_t acc[4][4];
#pragma unroll
  for (int i = 0; i < 4; i++)
#pragma unroll
    for (int j = 0; j < 4; j++)
#pragma unroll
      for (int r = 0; r < 4; r++) acc[i][j][r] = 0.f;

  GEMM_K_LOOP(A, W, m0, n0)

  int cn = lane & 15;
  int rb = (lane >> 4) * 4;
  int ysel = n0 / 768;                        // tile never straddles (768%128==0)
  float scale = (ysel == 0) ? 0.125f : 1.0f;  // fold 1/sqrt(64) into Q
#pragma unroll
  for (int i = 0; i < 4; i++)
#pragma unroll
    for (int j = 0; j < 4; j++)
#pragma unroll
      for (int r = 0; r < 4; r++) {
        int m = m0 + wm + i * 16 + rb + r;
        int n = n0 + wn + j * 16 + cn;
        unsigned short hv = f2bf(acc[i][j][r] * scale);
        int b = m >> 12, s = m & 4095;
        int nn = n - ysel * 768;
        int h = nn >> 6, d = nn & 63;
        if (ysel == 0)
          qb[(((size_t)b * HH + h) * SS + s) * HD + d] = hv;
        else if (ysel == 1)
          kb[(((size_t)b * HH + h) * SS + s) * HD + d] = hv;
        else
          vtb[(((size_t)b * HH + h) * HD + d) * SS + s] = hv;
      }
}

// ---------------------------------------------------------------------------
// Output projection, bf16 inputs, fp32 output, global_load_lds staging.
// ---------------------------------------------------------------------------
__global__ __launch_bounds__(256) void gemm_out_b(
    const unsigned short* __restrict__ A, const unsigned short* __restrict__ W,
    float* __restrict__ dst) {
  __shared__ unsigned short As[128 * 64];
  __shared__ unsigned short Bs[128 * 64];
  int tid = threadIdx.x;
  int m0 = blockIdx.x * 128;
  int n0 = blockIdx.y * 128;
  int lane = tid & 63;
  int w = tid >> 6;
  int wm = (w >> 1) * 64;
  int wn = (w & 1) * 64;

  float4_t acc[4][4];
#pragma unroll
  for (int i = 0; i < 4; i++)
#pragma unroll
    for (int j = 0; j < 4; j++)
#pragma unroll
      for (int r = 0; r < 4; r++) acc[i][j][r] = 0.f;

  GEMM_K_LOOP(A, W, m0, n0)

  int cn = lane & 15;
  int rb = (lane >> 4) * 4;
#pragma unroll
  for (int i = 0; i < 4; i++)
#pragma unroll
    for (int j = 0; j < 4; j++)
#pragma unroll
      for (int r = 0; r < 4; r++) {
        int m = m0 + wm + i * 16 + rb + r;
        int n = n0 + wn + j * 16 + cn;
        dst[(size_t)m * DD + n] = acc[i][j][r];
      }
}

// ---------------------------------------------------------------------------
// Block-sparse attention, fixed-max softmax (scores |s| <~ 2, exp-safe, and
// partials combine linearly). Heavy blocks (l=0,63) split 8 ways; each chunk
// writes unnormalized partial O + rowsum to scratch. Lights write bf16 ctx.
// Grid: ids 0..383 heavy chunks, 384..1871 lights.  (round-5-verified)
// ---------------------------------------------------------------------------
__global__ __launch_bounds__(256) void attn2(
    const unsigned short* __restrict__ q, const unsigned short* __restrict__ k,
    const unsigned short* __restrict__ vt, const int* __restrict__ graph,
    unsigned short* __restrict__ ctxb, float* __restrict__ part) {
  __shared__ unsigned short Ks[64 * LDK];      // K[key][d]
  __shared__ unsigned short Vs[64 * LDK];      // V^T[d][key]
  __shared__ unsigned short Ps[4][16 * LDK];   // per-wave P[q][key]

  int tid = threadIdx.x;
  int id = blockIdx.x;
  int b, h, l, nkb, heavy, chunk = 0, hid = 0;
  int list[8];
  if (id < 384) {
    heavy = 1;
    hid = id >> 3;
    chunk = id & 7;
    b = hid / 24;
    int r = hid % 24;
    h = r >> 1;
    l = (r & 1) ? (NBK - 1) : 0;
    nkb = 8;
#pragma unroll
    for (int i = 0; i < 8; i++) list[i] = chunk * 8 + i;
  } else {
    heavy = 0;
    int j = id - 384;
    b = j / 744;  // 744 = 12*62
    int r = j % 744;
    h = r / 62;
    l = 1 + r % 62;
    const int* g = graph + (((size_t)b * HH + h) * NBK + l) * MC;
    int n = 0;
    if (l == 1) {
      list[0] = 0; list[1] = 1; list[2] = 2; list[3] = NBK - 1; n = 4;
    } else if (l == NBK - 2) {
      list[0] = 0; list[1] = NBK - 3; list[2] = NBK - 2; list[3] = NBK - 1; n = 4;
    } else {
      list[0] = 0; list[1] = l - 1; list[2] = l; list[3] = l + 1;
      list[4] = NBK - 1; n = 5;
    }
    for (int m = 0; m < MC; m++) list[n++] = g[m];
    nkb = n;
  }
  size_t base = ((size_t)b * HH + h) * SS * HD;

  int lane = tid & 63;
  int w = tid >> 6;
  int lr = lane & 15;     // fragment m/n index
  int quad = lane >> 4;   // fragment k-group

  // Q fragments (A-layout) straight from global into registers (q pre-scaled).
  short8_t qa[2];
  {
    const unsigned short* qp =
        q + base + (size_t)(l * 64 + w * 16 + lr) * HD + quad * 8;
    qa[0] = *(const short8_t*)qp;
    qa[1] = *(const short8_t*)(qp + 32);
  }

  float4_t Ot[4];
  float ls[4];  // per-lane partial row sums (4 cols/row this lane)
#pragma unroll
  for (int t = 0; t < 4; t++)
#pragma unroll
    for (int r = 0; r < 4; r++) Ot[t][r] = 0.f;
#pragma unroll
  for (int r = 0; r < 4; r++) ls[r] = 0.f;

  // staging: each thread moves 2x16B for K and 2x16B for Vt
  int srow = tid >> 3;          // 0..31
  int scol = (tid & 7) * 8;     // 0..56

  uint4 kr0, kr1, vr0, vr1;
  {
    int kb = list[0];
    const unsigned short* kp = k + base + (size_t)(kb * 64 + srow) * HD + scol;
    const unsigned short* vp = vt + base + (size_t)srow * SS + kb * 64 + scol;
    kr0 = *(const uint4*)kp;
    kr1 = *(const uint4*)(kp + 32 * HD);
    vr0 = *(const uint4*)vp;
    vr1 = *(const uint4*)(vp + 32 * SS);
  }

  for (int t = 0; t < nkb; t++) {
    *(uint4*)&Ks[srow * LDK + scol] = kr0;
    *(uint4*)&Ks[(srow + 32) * LDK + scol] = kr1;
    *(uint4*)&Vs[srow * LDK + scol] = vr0;
    *(uint4*)&Vs[(srow + 32) * LDK + scol] = vr1;
    __syncthreads();

    if (t + 1 < nkb) {  // prefetch next; hides behind compute
      int kb = list[t + 1];
      const unsigned short* kp = k + base + (size_t)(kb * 64 + srow) * HD + scol;
      const unsigned short* vp = vt + base + (size_t)srow * SS + kb * 64 + scol;
      kr0 = *(const uint4*)kp;
      kr1 = *(const uint4*)(kp + 32 * HD);
      vr0 = *(const uint4*)vp;
      vr1 = *(const uint4*)(vp + 32 * SS);
    }

    // S = Q K^T
    float4_t st[4];
#pragma unroll
    for (int tt = 0; tt < 4; tt++) {
#pragma unroll
      for (int r = 0; r < 4; r++) st[tt][r] = 0.f;
      short8_t kb0 = *(const short8_t*)&Ks[(tt * 16 + lr) * LDK + quad * 8];
      short8_t kb1 = *(const short8_t*)&Ks[(tt * 16 + lr) * LDK + quad * 8 + 32];
      st[tt] = __builtin_amdgcn_mfma_f32_16x16x32_bf16(qa[0], kb0, st[tt], 0, 0, 0);
      st[tt] = __builtin_amdgcn_mfma_f32_16x16x32_bf16(qa[1], kb1, st[tt], 0, 0, 0);
    }

    // fixed-max softmax: p = exp(s); per-lane partial sums, no shuffles.
#pragma unroll
    for (int tt = 0; tt < 4; tt++)
#pragma unroll
      for (int r = 0; r < 4; r++) {
        float p = __expf(st[tt][r]);
        st[tt][r] = p;
        ls[r] += p;
        Ps[w][(quad * 4 + r) * LDK + tt * 16 + lr] = f2bf(p);
      }

    // O += P V
#pragma unroll
    for (int s = 0; s < 2; s++) {
      short8_t pa = *(const short8_t*)&Ps[w][lr * LDK + s * 32 + quad * 8];
#pragma unroll
      for (int tt = 0; tt < 4; tt++) {
        short8_t vb =
            *(const short8_t*)&Vs[(tt * 16 + lr) * LDK + s * 32 + quad * 8];
        Ot[tt] = __builtin_amdgcn_mfma_f32_16x16x32_bf16(pa, vb, Ot[tt], 0, 0, 0);
      }
    }
    __syncthreads();
  }

  // reduce row sums across the 16 lanes holding each row
#pragma unroll
  for (int r = 0; r < 4; r++)
#pragma unroll
    for (int off = 1; off < 16; off <<= 1) ls[r] += __shfl_xor(ls[r], off);

  if (!heavy) {
#pragma unroll
    for (int r = 0; r < 4; r++) {
      float inv = 1.f / ls[r];
      size_t row = (size_t)b * SS + (size_t)l * 64 + w * 16 + quad * 4 + r;
#pragma unroll
      for (int tt = 0; tt < 4; tt++)
        ctxb[row * DD + h * HD + tt * 16 + lr] = f2bf(Ot[tt][r] * inv);
    }
  } else {
    float* pb = part + ((size_t)hid * 8 + chunk) * 4160;  // 64*64 O + 64 lsum
#pragma unroll
    for (int r = 0; r < 4; r++) {
      int rowi = w * 16 + quad * 4 + r;
#pragma unroll
      for (int tt = 0; tt < 4; tt++)
        pb[rowi * 64 + tt * 16 + lr] = Ot[tt][r];
      if (lr == 0) pb[4096 + rowi] = ls[r];
    }
  }
}

// ---------------------------------------------------------------------------
// Combine the 8 partials of each heavy block, normalize, write bf16 ctx.
// ---------------------------------------------------------------------------
__global__ __launch_bounds__(256) void reduce_heavy(
    const float* __restrict__ part, unsigned short* __restrict__ ctxb) {
  __shared__ float lrow[64];
  int hid = blockIdx.x;
  int tid = threadIdx.x;
  int b = hid / 24;
  int r = hid % 24;
  int h = r >> 1;
  int l = (r & 1) ? (NBK - 1) : 0;
  const float* pb = part + (size_t)hid * 8 * 4160;
  if (tid < 64) {
    float s = 0.f;
#pragma unroll
    for (int c = 0; c < 8; c++) s += pb[c * 4160 + 4096 + tid];
    lrow[tid] = s;
  }
  __syncthreads();
#pragma unroll
  for (int e = tid; e < 4096; e += 256) {
    float o = 0.f;
#pragma unroll
    for (int c = 0; c < 8; c++) o += pb[c * 4160 + e];
    int rowi = e >> 6, col = e & 63;
    size_t row = (size_t)b * SS + (size_t)l * 64 + rowi;
    ctxb[row * DD + h * HD + col] = f2bf(o / lrow[rowi]);
  }
}

extern "C" void kernel_launch(void* const* d_in, const int* in_sizes, int n_in,
                              void* d_out, int out_size, void* d_ws,
                              size_t ws_size, hipStream_t stream) {
  const float* hs = (const float*)d_in[0];
  const float* Wq = (const float*)d_in[1];
  const float* Wk = (const float*)d_in[2];
  const float* Wv = (const float*)d_in[3];
  const float* Wo = (const float*)d_in[4];
  const int* graph = (const int*)d_in[10];

  const size_t NHS = (size_t)BB * SS * DD;  // 6291456
  unsigned short* hsb = (unsigned short*)d_ws;
  unsigned short* wqkvb = hsb + NHS;            // 3*768*768
  unsigned short* wob = wqkvb + 3 * 768 * 768;  // 768*768
  unsigned short* qb = wob + 768 * 768;
  unsigned short* kb = qb + NHS;
  unsigned short* vtb = kb + NHS;
  unsigned short* ctxb = vtb + NHS;
  float* part = (float*)(ctxb + NHS);  // 48*8*4160 floats

  cvt_all<<<8448, 256, 0, stream>>>(hs, Wq, Wk, Wv, Wo, hsb, wqkvb, wob);
  gemm_qkv_b<<<dim3(64, 18, 1), 256, 0, stream>>>(hsb, wqkvb, qb, kb, vtb);
  attn2<<<1872, 256, 0, stream>>>(qb, kb, vtb, graph, ctxb, part);
  reduce_heavy<<<48, 256, 0, stream>>>(part, ctxb);
  gemm_out_b<<<dim3(64, 6, 1), 256, 0, stream>>>(ctxb, wob, (float*)d_out);
}

// Round 9
// 213.417 us; speedup vs baseline: 1.7305x; 1.0566x over previous
//
#include <hip/hip_runtime.h>
#include <hip/hip_bf16.h>

#define BB 2
#define HH 12
#define SS 4096
#define DD 768
#define HD 64
#define NBK 64
#define MC 3

typedef __attribute__((ext_vector_type(8))) short short8_t;
typedef __attribute__((ext_vector_type(4))) float float4_t;

__device__ __forceinline__ unsigned short f2bf(float f) {
  union { float f; unsigned u; } c;
  c.f = f;
  unsigned u = c.u + 0x7FFFu + ((c.u >> 16) & 1u);  // RNE
  return (unsigned short)(u >> 16);
}

// async 16B global -> LDS (gfx950). LDS dest = wave-uniform base + lane*16.
__device__ __forceinline__ void gload16(const unsigned short* gp,
                                        unsigned short* lp) {
  __builtin_amdgcn_global_load_lds(
      (const __attribute__((address_space(1))) unsigned int*)gp,
      (__attribute__((address_space(3))) unsigned int*)lp, 16, 0, 0);
}

#define LDK 72  // padded stride (attn kernel only)

// ---------------------------------------------------------------------------
// One-shot fp32 -> bf16 conversion: hs (8192x768), Wq|Wk|Wv packed (2304x768),
// Wo (768x768). One float4 per thread.
// ---------------------------------------------------------------------------
__global__ __launch_bounds__(256) void cvt_all(
    const float* __restrict__ hs, const float* __restrict__ Wq,
    const float* __restrict__ Wk, const float* __restrict__ Wv,
    const float* __restrict__ Wo, unsigned short* __restrict__ hsb,
    unsigned short* __restrict__ wqkvb, unsigned short* __restrict__ wob) {
  long i4 = (long)blockIdx.x * 256 + threadIdx.x;  // float4 index
  const float* src;
  unsigned short* dst;
  if (i4 < 1572864) {          // hs: 6291456 floats
    src = hs + i4 * 4;
    dst = hsb + i4 * 4;
  } else {
    long r = i4 - 1572864;
    int w = (int)(r / 147456);  // 0..3 : Wq,Wk,Wv,Wo (589824 floats each)
    long e = r % 147456;
    src = (w == 0 ? Wq : w == 1 ? Wk : w == 2 ? Wv : Wo) + e * 4;
    dst = (w < 3) ? (wqkvb + (long)w * 589824 + e * 4) : (wob + e * 4);
  }
  float4_t v = *(const float4_t*)src;
  uint2 p;
  p.x = (unsigned)f2bf(v[0]) | ((unsigned)f2bf(v[1]) << 16);
  p.y = (unsigned)f2bf(v[2]) | ((unsigned)f2bf(v[3]) << 16);
  *(uint2*)dst = p;
}

// ---------------------------------------------------------------------------
// Shared staging + fragment-read pieces (m97-style async, XOR-swizzled LDS).
// LDS row r = 64 shorts (8 chunks of 16B); global chunk c at slot c^(r&7).
// ---------------------------------------------------------------------------
#define STAGE_TILE(A_, B_, m0_, n0_, kt_)                                     \
  {                                                                           \
    int rr_ = lane >> 3;                                                      \
    int cg_ = (lane & 7) ^ rr_;                                               \
    _Pragma("unroll") for (int u = 0; u < 4; u++) {                           \
      int g_ = w * 4 + u;                                                     \
      gload16(A_ + (size_t)(m0_ + g_ * 8 + rr_) * DD + kt_ + cg_ * 8,         \
              &As[g_ * 512]);                                                 \
      gload16(B_ + (size_t)(n0_ + g_ * 8 + rr_) * DD + kt_ + cg_ * 8,         \
              &Bs[g_ * 512]);                                                 \
    }                                                                         \
  }

#define LOAD_FRAGS(kk_)                                                       \
  int fr = lane & 15;                                                         \
  int qd = lane >> 4;                                                         \
  int cb = qd + ((kk_) >> 3);                                                 \
  short8_t af[4], bfr[4];                                                     \
  _Pragma("unroll") for (int i = 0; i < 4; i++) {                             \
    int r_ = wm + i * 16 + fr;                                                \
    af[i] = *(const short8_t*)&As[r_ * 64 + (cb ^ (fr & 7)) * 8];             \
  }                                                                           \
  _Pragma("unroll") for (int j = 0; j < 4; j++) {                             \
    int r_ = wn + j * 16 + fr;                                                \
    bfr[j] = *(const short8_t*)&Bs[r_ * 64 + (cb ^ (fr & 7)) * 8];            \
  }

// ---------------------------------------------------------------------------
// QKV projection, bf16 inputs, global_load_lds staging.
// Q/K tiles: SWAPPED operands (compute C^T) so the reg dim spans d ->
// packed uint2 stores to [b][h][s][d]. V: normal orientation, reg dim spans
// s -> packed uint2 stores to transposed [b][h][d][s].
// ---------------------------------------------------------------------------
__global__ __launch_bounds__(256) void gemm_qkv_b(
    const unsigned short* __restrict__ A, const unsigned short* __restrict__ W,
    unsigned short* __restrict__ qb, unsigned short* __restrict__ kb,
    unsigned short* __restrict__ vtb) {
  __shared__ unsigned short As[128 * 64];
  __shared__ unsigned short Bs[128 * 64];
  int tid = threadIdx.x;
  int m0 = blockIdx.x * 128;
  int n0 = blockIdx.y * 128;  // 0..2176
  int lane = tid & 63;
  int w = tid >> 6;
  int wm = (w >> 1) * 64;
  int wn = (w & 1) * 64;
  int ysel = n0 / 768;  // tile never straddles (768 % 128 == 0)

  float4_t acc[4][4];
#pragma unroll
  for (int i = 0; i < 4; i++)
#pragma unroll
    for (int j = 0; j < 4; j++)
#pragma unroll
      for (int r = 0; r < 4; r++) acc[i][j][r] = 0.f;

  if (ysel < 2) {
    // ---- Q/K: swapped-operand K-loop; acc[j][i] = C^T tile ----
    for (int kt = 0; kt < DD; kt += 64) {
      __syncthreads();
      STAGE_TILE(A, W, m0, n0, kt)
      __syncthreads();
#pragma unroll
      for (int kk = 0; kk < 64; kk += 32) {
        LOAD_FRAGS(kk)
#pragma unroll
        for (int i = 0; i < 4; i++)
#pragma unroll
          for (int j = 0; j < 4; j++)
            acc[j][i] = __builtin_amdgcn_mfma_f32_16x16x32_bf16(
                bfr[j], af[i], acc[j][i], 0, 0, 0);
      }
    }
    int cn = lane & 15;
    int quad = lane >> 4;
    float scale = (ysel == 0) ? 0.125f : 1.0f;  // fold 1/sqrt(64) into Q
    unsigned short* dst = (ysel == 0) ? qb : kb;
    int nb0 = n0 - ysel * 768;
#pragma unroll
    for (int j = 0; j < 4; j++)
#pragma unroll
      for (int i = 0; i < 4; i++) {
        int m = m0 + wm + i * 16 + cn;            // s dimension
        int nn = nb0 + wn + j * 16 + quad * 4;    // d dimension (4-consec)
        int b = m >> 12, s = m & 4095;
        int h = nn >> 6, d0 = nn & 63;
        uint2 p;
        p.x = (unsigned)f2bf(acc[j][i][0] * scale) |
              ((unsigned)f2bf(acc[j][i][1] * scale) << 16);
        p.y = (unsigned)f2bf(acc[j][i][2] * scale) |
              ((unsigned)f2bf(acc[j][i][3] * scale) << 16);
        *(uint2*)&dst[(((size_t)b * HH + h) * SS + s) * HD + d0] = p;
      }
  } else {
    // ---- V: normal K-loop; reg dim spans s (contig in [b][h][d][s]) ----
    for (int kt = 0; kt < DD; kt += 64) {
      __syncthreads();
      STAGE_TILE(A, W, m0, n0, kt)
      __syncthreads();
#pragma unroll
      for (int kk = 0; kk < 64; kk += 32) {
        LOAD_FRAGS(kk)
#pragma unroll
        for (int i = 0; i < 4; i++)
#pragma unroll
          for (int j = 0; j < 4; j++)
            acc[i][j] = __builtin_amdgcn_mfma_f32_16x16x32_bf16(
                af[i], bfr[j], acc[i][j], 0, 0, 0);
      }
    }
    int cn = lane & 15;
    int quad = lane >> 4;
    int nb0 = n0 - 1536;
#pragma unroll
    for (int i = 0; i < 4; i++)
#pragma unroll
      for (int j = 0; j < 4; j++) {
        int m = m0 + wm + i * 16 + quad * 4;      // s base (4-consec)
        int nn = nb0 + wn + j * 16 + cn;          // d dimension
        int b = m >> 12, s0 = m & 4095;
        int h = nn >> 6, d = nn & 63;
        uint2 p;
        p.x = (unsigned)f2bf(acc[i][j][0]) |
              ((unsigned)f2bf(acc[i][j][1]) << 16);
        p.y = (unsigned)f2bf(acc[i][j][2]) |
              ((unsigned)f2bf(acc[i][j][3]) << 16);
        *(uint2*)&vtb[(((size_t)b * HH + h) * HD + d) * SS + s0] = p;
      }
  }
}

// ---------------------------------------------------------------------------
// Output projection, bf16 inputs, fp32 output (coalesced), async staging.
// ---------------------------------------------------------------------------
__global__ __launch_bounds__(256) void gemm_out_b(
    const unsigned short* __restrict__ A, const unsigned short* __restrict__ W,
    float* __restrict__ dst) {
  __shared__ unsigned short As[128 * 64];
  __shared__ unsigned short Bs[128 * 64];
  int tid = threadIdx.x;
  int m0 = blockIdx.x * 128;
  int n0 = blockIdx.y * 128;
  int lane = tid & 63;
  int w = tid >> 6;
  int wm = (w >> 1) * 64;
  int wn = (w & 1) * 64;

  float4_t acc[4][4];
#pragma unroll
  for (int i = 0; i < 4; i++)
#pragma unroll
    for (int j = 0; j < 4; j++)
#pragma unroll
      for (int r = 0; r < 4; r++) acc[i][j][r] = 0.f;

  for (int kt = 0; kt < DD; kt += 64) {
    __syncthreads();
    STAGE_TILE(A, W, m0, n0, kt)
    __syncthreads();
#pragma unroll
    for (int kk = 0; kk < 64; kk += 32) {
      LOAD_FRAGS(kk)
#pragma unroll
      for (int i = 0; i < 4; i++)
#pragma unroll
        for (int j = 0; j < 4; j++)
          acc[i][j] = __builtin_amdgcn_mfma_f32_16x16x32_bf16(
              af[i], bfr[j], acc[i][j], 0, 0, 0);
    }
  }

  int cn = lane & 15;
  int rb = (lane >> 4) * 4;
#pragma unroll
  for (int i = 0; i < 4; i++)
#pragma unroll
    for (int j = 0; j < 4; j++)
#pragma unroll
      for (int r = 0; r < 4; r++) {
        int m = m0 + wm + i * 16 + rb + r;
        int n = n0 + wn + j * 16 + cn;
        dst[(size_t)m * DD + n] = acc[i][j][r];
      }
}

// ---------------------------------------------------------------------------
// Block-sparse attention, fixed-max softmax (scores |s| <~ 2, exp-safe, and
// partials combine linearly). Heavy blocks (l=0,63) split 8 ways; each chunk
// writes unnormalized partial O + rowsum to scratch. Lights write bf16 ctx.
// Grid: ids 0..383 heavy chunks, 384..1871 lights.  (round-5-verified)
// ---------------------------------------------------------------------------
__global__ __launch_bounds__(256) void attn2(
    const unsigned short* __restrict__ q, const unsigned short* __restrict__ k,
    const unsigned short* __restrict__ vt, const int* __restrict__ graph,
    unsigned short* __restrict__ ctxb, float* __restrict__ part) {
  __shared__ unsigned short Ks[64 * LDK];      // K[key][d]
  __shared__ unsigned short Vs[64 * LDK];      // V^T[d][key]
  __shared__ unsigned short Ps[4][16 * LDK];   // per-wave P[q][key]

  int tid = threadIdx.x;
  int id = blockIdx.x;
  int b, h, l, nkb, heavy, chunk = 0, hid = 0;
  int list[8];
  if (id < 384) {
    heavy = 1;
    hid = id >> 3;
    chunk = id & 7;
    b = hid / 24;
    int r = hid % 24;
    h = r >> 1;
    l = (r & 1) ? (NBK - 1) : 0;
    nkb = 8;
#pragma unroll
    for (int i = 0; i < 8; i++) list[i] = chunk * 8 + i;
  } else {
    heavy = 0;
    int j = id - 384;
    b = j / 744;  // 744 = 12*62
    int r = j % 744;
    h = r / 62;
    l = 1 + r % 62;
    const int* g = graph + (((size_t)b * HH + h) * NBK + l) * MC;
    int n = 0;
    if (l == 1) {
      list[0] = 0; list[1] = 1; list[2] = 2; list[3] = NBK - 1; n = 4;
    } else if (l == NBK - 2) {
      list[0] = 0; list[1] = NBK - 3; list[2] = NBK - 2; list[3] = NBK - 1; n = 4;
    } else {
      list[0] = 0; list[1] = l - 1; list[2] = l; list[3] = l + 1;
      list[4] = NBK - 1; n = 5;
    }
    for (int m = 0; m < MC; m++) list[n++] = g[m];
    nkb = n;
  }
  size_t base = ((size_t)b * HH + h) * SS * HD;

  int lane = tid & 63;
  int w = tid >> 6;
  int lr = lane & 15;     // fragment m/n index
  int quad = lane >> 4;   // fragment k-group

  // Q fragments (A-layout) straight from global into registers (q pre-scaled).
  short8_t qa[2];
  {
    const unsigned short* qp =
        q + base + (size_t)(l * 64 + w * 16 + lr) * HD + quad * 8;
    qa[0] = *(const short8_t*)qp;
    qa[1] = *(const short8_t*)(qp + 32);
  }

  float4_t Ot[4];
  float ls[4];  // per-lane partial row sums (4 cols/row this lane)
#pragma unroll
  for (int t = 0; t < 4; t++)
#pragma unroll
    for (int r = 0; r < 4; r++) Ot[t][r] = 0.f;
#pragma unroll
  for (int r = 0; r < 4; r++) ls[r] = 0.f;

  // staging: each thread moves 2x16B for K and 2x16B for Vt
  int srow = tid >> 3;          // 0..31
  int scol = (tid & 7) * 8;     // 0..56

  uint4 kr0, kr1, vr0, vr1;
  {
    int kb = list[0];
    const unsigned short* kp = k + base + (size_t)(kb * 64 + srow) * HD + scol;
    const unsigned short* vp = vt + base + (size_t)srow * SS + kb * 64 + scol;
    kr0 = *(const uint4*)kp;
    kr1 = *(const uint4*)(kp + 32 * HD);
    vr0 = *(const uint4*)vp;
    vr1 = *(const uint4*)(vp + 32 * SS);
  }

  for (int t = 0; t < nkb; t++) {
    *(uint4*)&Ks[srow * LDK + scol] = kr0;
    *(uint4*)&Ks[(srow + 32) * LDK + scol] = kr1;
    *(uint4*)&Vs[srow * LDK + scol] = vr0;
    *(uint4*)&Vs[(srow + 32) * LDK + scol] = vr1;
    __syncthreads();

    if (t + 1 < nkb) {  // prefetch next; hides behind compute
      int kb = list[t + 1];
      const unsigned short* kp = k + base + (size_t)(kb * 64 + srow) * HD + scol;
      const unsigned short* vp = vt + base + (size_t)srow * SS + kb * 64 + scol;
      kr0 = *(const uint4*)kp;
      kr1 = *(const uint4*)(kp + 32 * HD);
      vr0 = *(const uint4*)vp;
      vr1 = *(const uint4*)(vp + 32 * SS);
    }

    // S = Q K^T
    float4_t st[4];
#pragma unroll
    for (int tt = 0; tt < 4; tt++) {
#pragma unroll
      for (int r = 0; r < 4; r++) st[tt][r] = 0.f;
      short8_t kb0 = *(const short8_t*)&Ks[(tt * 16 + lr) * LDK + quad * 8];
      short8_t kb1 = *(const short8_t*)&Ks[(tt * 16 + lr) * LDK + quad * 8 + 32];
      st[tt] = __builtin_amdgcn_mfma_f32_16x16x32_bf16(qa[0], kb0, st[tt], 0, 0, 0);
      st[tt] = __builtin_amdgcn_mfma_f32_16x16x32_bf16(qa[1], kb1, st[tt], 0, 0, 0);
    }

    // fixed-max softmax: p = exp(s); per-lane partial sums, no shuffles.
#pragma unroll
    for (int tt = 0; tt < 4; tt++)
#pragma unroll
      for (int r = 0; r < 4; r++) {
        float p = __expf(st[tt][r]);
        st[tt][r] = p;
        ls[r] += p;
        Ps[w][(quad * 4 + r) * LDK + tt * 16 + lr] = f2bf(p);
      }

    // O += P V
#pragma unroll
    for (int s = 0; s < 2; s++) {
      short8_t pa = *(const short8_t*)&Ps[w][lr * LDK + s * 32 + quad * 8];
#pragma unroll
      for (int tt = 0; tt < 4; tt++) {
        short8_t vb =
            *(const short8_t*)&Vs[(tt * 16 + lr) * LDK + s * 32 + quad * 8];
        Ot[tt] = __builtin_amdgcn_mfma_f32_16x16x32_bf16(pa, vb, Ot[tt], 0, 0, 0);
      }
    }
    __syncthreads();
  }

  // reduce row sums across the 16 lanes holding each row
#pragma unroll
  for (int r = 0; r < 4; r++)
#pragma unroll
    for (int off = 1; off < 16; off <<= 1) ls[r] += __shfl_xor(ls[r], off);

  if (!heavy) {
#pragma unroll
    for (int r = 0; r < 4; r++) {
      float inv = 1.f / ls[r];
      size_t row = (size_t)b * SS + (size_t)l * 64 + w * 16 + quad * 4 + r;
#pragma unroll
      for (int tt = 0; tt < 4; tt++)
        ctxb[row * DD + h * HD + tt * 16 + lr] = f2bf(Ot[tt][r] * inv);
    }
  } else {
    float* pb = part + ((size_t)hid * 8 + chunk) * 4160;  // 64*64 O + 64 lsum
#pragma unroll
    for (int r = 0; r < 4; r++) {
      int rowi = w * 16 + quad * 4 + r;
#pragma unroll
      for (int tt = 0; tt < 4; tt++)
        pb[rowi * 64 + tt * 16 + lr] = Ot[tt][r];
      if (lr == 0) pb[4096 + rowi] = ls[r];
    }
  }
}

// ---------------------------------------------------------------------------
// Combine the 8 partials of each heavy block, normalize, write bf16 ctx.
// ---------------------------------------------------------------------------
__global__ __launch_bounds__(256) void reduce_heavy(
    const float* __restrict__ part, unsigned short* __restrict__ ctxb) {
  __shared__ float lrow[64];
  int hid = blockIdx.x;
  int tid = threadIdx.x;
  int b = hid / 24;
  int r = hid % 24;
  int h = r >> 1;
  int l = (r & 1) ? (NBK - 1) : 0;
  const float* pb = part + (size_t)hid * 8 * 4160;
  if (tid < 64) {
    float s = 0.f;
#pragma unroll
    for (int c = 0; c < 8; c++) s += pb[c * 4160 + 4096 + tid];
    lrow[tid] = s;
  }
  __syncthreads();
#pragma unroll
  for (int e = tid; e < 4096; e += 256) {
    float o = 0.f;
#pragma unroll
    for (int c = 0; c < 8; c++) o += pb[c * 4160 + e];
    int rowi = e >> 6, col = e & 63;
    size_t row = (size_t)b * SS + (size_t)l * 64 + rowi;
    ctxb[row * DD + h * HD + col] = f2bf(o / lrow[rowi]);
  }
}

extern "C" void kernel_launch(void* const* d_in, const int* in_sizes, int n_in,
                              void* d_out, int out_size, void* d_ws,
                              size_t ws_size, hipStream_t stream) {
  const float* hs = (const float*)d_in[0];
  const float* Wq = (const float*)d_in[1];
  const float* Wk = (const float*)d_in[2];
  const float* Wv = (const float*)d_in[3];
  const float* Wo = (const float*)d_in[4];
  const int* graph = (const int*)d_in[10];

  const size_t NHS = (size_t)BB * SS * DD;  // 6291456
  unsigned short* hsb = (unsigned short*)d_ws;
  unsigned short* wqkvb = hsb + NHS;            // 3*768*768
  unsigned short* wob = wqkvb + 3 * 768 * 768;  // 768*768
  unsigned short* qb = wob + 768 * 768;
  unsigned short* kb = qb + NHS;
  unsigned short* vtb = kb + NHS;
  unsigned short* ctxb = vtb + NHS;
  float* part = (float*)(ctxb + NHS);  // 48*8*4160 floats

  cvt_all<<<8448, 256, 0, stream>>>(hs, Wq, Wk, Wv, Wo, hsb, wqkvb, wob);
  gemm_qkv_b<<<dim3(64, 18, 1), 256, 0, stream>>>(hsb, wqkvb, qb, kb, vtb);
  attn2<<<1872, 256, 0, stream>>>(qb, kb, vtb, graph, ctxb, part);
  reduce_heavy<<<48, 256, 0, stream>>>(part, ctxb);
  gemm_out_b<<<dim3(64, 6, 1), 256, 0, stream>>>(ctxb, wob, (float*)d_out);
}

// Round 10
// 210.683 us; speedup vs baseline: 1.7529x; 1.0130x over previous
//
#include <hip/hip_runtime.h>
#include <hip/hip_bf16.h>

#define BB 2
#define HH 12
#define SS 4096
#define DD 768
#define HD 64
#define NBK 64
#define MC 3

typedef __attribute__((ext_vector_type(8))) short short8_t;
typedef __attribute__((ext_vector_type(4))) float float4_t;

__device__ __forceinline__ unsigned short f2bf(float f) {
  union { float f; unsigned u; } c;
  c.f = f;
  unsigned u = c.u + 0x7FFFu + ((c.u >> 16) & 1u);  // RNE
  return (unsigned short)(u >> 16);
}

// async 16B global -> LDS (gfx950). LDS dest = wave-uniform base + lane*16.
__device__ __forceinline__ void gload16(const unsigned short* gp,
                                        unsigned short* lp) {
  __builtin_amdgcn_global_load_lds(
      (const __attribute__((address_space(1))) unsigned int*)gp,
      (__attribute__((address_space(3))) unsigned int*)lp, 16, 0, 0);
}

#define LDK 72  // padded stride (attn kernel only)

// ---------------------------------------------------------------------------
// One-shot fp32 -> bf16 conversion: hs (8192x768), Wq|Wk|Wv packed (2304x768),
// Wo (768x768). One float4 per thread.
// ---------------------------------------------------------------------------
__global__ __launch_bounds__(256) void cvt_all(
    const float* __restrict__ hs, const float* __restrict__ Wq,
    const float* __restrict__ Wk, const float* __restrict__ Wv,
    const float* __restrict__ Wo, unsigned short* __restrict__ hsb,
    unsigned short* __restrict__ wqkvb, unsigned short* __restrict__ wob) {
  long i4 = (long)blockIdx.x * 256 + threadIdx.x;  // float4 index
  const float* src;
  unsigned short* dst;
  if (i4 < 1572864) {          // hs: 6291456 floats
    src = hs + i4 * 4;
    dst = hsb + i4 * 4;
  } else {
    long r = i4 - 1572864;
    int w = (int)(r / 147456);  // 0..3 : Wq,Wk,Wv,Wo (589824 floats each)
    long e = r % 147456;
    src = (w == 0 ? Wq : w == 1 ? Wk : w == 2 ? Wv : Wo) + e * 4;
    dst = (w < 3) ? (wqkvb + (long)w * 589824 + e * 4) : (wob + e * 4);
  }
  float4_t v = *(const float4_t*)src;
  uint2 p;
  p.x = (unsigned)f2bf(v[0]) | ((unsigned)f2bf(v[1]) << 16);
  p.y = (unsigned)f2bf(v[2]) | ((unsigned)f2bf(v[3]) << 16);
  *(uint2*)dst = p;
}

// ---------------------------------------------------------------------------
// GEMM staging/fragment helpers. Double-buffered XOR-swizzled LDS.
// LDS row r = 64 shorts (8 chunks of 16B); global chunk c at slot c^(r&7).
// Single barrier per K-iter: prefetch of kt+64 issues AFTER the barrier, so
// it stays in flight during compute and drains at the NEXT barrier.
// ---------------------------------------------------------------------------
#define STAGE_TILE(buf_, A_, B_, m0_, n0_, kt_)                               \
  {                                                                           \
    int rr_ = lane >> 3;                                                      \
    int cg_ = (lane & 7) ^ rr_;                                               \
    _Pragma("unroll") for (int u = 0; u < 4; u++) {                           \
      int g_ = w * 4 + u;                                                     \
      gload16(A_ + (size_t)(m0_ + g_ * 8 + rr_) * DD + kt_ + cg_ * 8,         \
              &As[buf_][g_ * 512]);                                           \
      gload16(B_ + (size_t)(n0_ + g_ * 8 + rr_) * DD + kt_ + cg_ * 8,         \
              &Bs[buf_][g_ * 512]);                                           \
    }                                                                         \
  }

#define LOAD_FRAGS(buf_, kk_)                                                 \
  int fr = lane & 15;                                                         \
  int qd = lane >> 4;                                                         \
  int cb = qd + ((kk_) >> 3);                                                 \
  short8_t af[4], bfr[4];                                                     \
  _Pragma("unroll") for (int i = 0; i < 4; i++) {                             \
    int r_ = wm + i * 16 + fr;                                                \
    af[i] = *(const short8_t*)&As[buf_][r_ * 64 + (cb ^ (fr & 7)) * 8];       \
  }                                                                           \
  _Pragma("unroll") for (int j = 0; j < 4; j++) {                             \
    int r_ = wn + j * 16 + fr;                                                \
    bfr[j] = *(const short8_t*)&Bs[buf_][r_ * 64 + (cb ^ (fr & 7)) * 8];      \
  }

// ---------------------------------------------------------------------------
// QKV projection, bf16 inputs, dbuf async staging, 1 barrier/iter.
// Q/K tiles: SWAPPED operands (C^T, reg dim spans d) -> packed uint2 stores.
// V: normal orientation (reg dim spans s) -> packed uint2 stores transposed.
// ---------------------------------------------------------------------------
__global__ __launch_bounds__(256) void gemm_qkv_b(
    const unsigned short* __restrict__ A, const unsigned short* __restrict__ W,
    unsigned short* __restrict__ qb, unsigned short* __restrict__ kb,
    unsigned short* __restrict__ vtb) {
  __shared__ unsigned short As[2][128 * 64];
  __shared__ unsigned short Bs[2][128 * 64];
  int tid = threadIdx.x;
  int m0 = blockIdx.x * 128;
  int n0 = blockIdx.y * 128;  // 0..2176
  int lane = tid & 63;
  int w = tid >> 6;
  int wm = (w >> 1) * 64;
  int wn = (w & 1) * 64;
  int ysel = n0 / 768;  // tile never straddles (768 % 128 == 0)

  float4_t acc[4][4];
#pragma unroll
  for (int i = 0; i < 4; i++)
#pragma unroll
    for (int j = 0; j < 4; j++)
#pragma unroll
      for (int r = 0; r < 4; r++) acc[i][j][r] = 0.f;

  STAGE_TILE(0, A, W, m0, n0, 0)
  int p = 0;

  if (ysel < 2) {
    // ---- Q/K: swapped-operand K-loop; acc[j][i] = C^T tile ----
    for (int kt = 0; kt < DD; kt += 64) {
      __syncthreads();  // drains stage(kt); waves done reading buf p^1
      if (kt + 64 < DD) STAGE_TILE(p ^ 1, A, W, m0, n0, kt + 64)
#pragma unroll
      for (int kk = 0; kk < 64; kk += 32) {
        LOAD_FRAGS(p, kk)
#pragma unroll
        for (int i = 0; i < 4; i++)
#pragma unroll
          for (int j = 0; j < 4; j++)
            acc[j][i] = __builtin_amdgcn_mfma_f32_16x16x32_bf16(
                bfr[j], af[i], acc[j][i], 0, 0, 0);
      }
      p ^= 1;
    }
    int cn = lane & 15;
    int quad = lane >> 4;
    float scale = (ysel == 0) ? 0.125f : 1.0f;  // fold 1/sqrt(64) into Q
    unsigned short* dst = (ysel == 0) ? qb : kb;
    int nb0 = n0 - ysel * 768;
#pragma unroll
    for (int j = 0; j < 4; j++)
#pragma unroll
      for (int i = 0; i < 4; i++) {
        int m = m0 + wm + i * 16 + cn;            // s dimension
        int nn = nb0 + wn + j * 16 + quad * 4;    // d dimension (4-consec)
        int b = m >> 12, s = m & 4095;
        int h = nn >> 6, d0 = nn & 63;
        uint2 pk;
        pk.x = (unsigned)f2bf(acc[j][i][0] * scale) |
               ((unsigned)f2bf(acc[j][i][1] * scale) << 16);
        pk.y = (unsigned)f2bf(acc[j][i][2] * scale) |
               ((unsigned)f2bf(acc[j][i][3] * scale) << 16);
        *(uint2*)&dst[(((size_t)b * HH + h) * SS + s) * HD + d0] = pk;
      }
  } else {
    // ---- V: normal K-loop; reg dim spans s (contig in [b][h][d][s]) ----
    for (int kt = 0; kt < DD; kt += 64) {
      __syncthreads();
      if (kt + 64 < DD) STAGE_TILE(p ^ 1, A, W, m0, n0, kt + 64)
#pragma unroll
      for (int kk = 0; kk < 64; kk += 32) {
        LOAD_FRAGS(p, kk)
#pragma unroll
        for (int i = 0; i < 4; i++)
#pragma unroll
          for (int j = 0; j < 4; j++)
            acc[i][j] = __builtin_amdgcn_mfma_f32_16x16x32_bf16(
                af[i], bfr[j], acc[i][j], 0, 0, 0);
      }
      p ^= 1;
    }
    int cn = lane & 15;
    int quad = lane >> 4;
    int nb0 = n0 - 1536;
#pragma unroll
    for (int i = 0; i < 4; i++)
#pragma unroll
      for (int j = 0; j < 4; j++) {
        int m = m0 + wm + i * 16 + quad * 4;      // s base (4-consec)
        int nn = nb0 + wn + j * 16 + cn;          // d dimension
        int b = m >> 12, s0 = m & 4095;
        int h = nn >> 6, d = nn & 63;
        uint2 pk;
        pk.x = (unsigned)f2bf(acc[i][j][0]) |
               ((unsigned)f2bf(acc[i][j][1]) << 16);
        pk.y = (unsigned)f2bf(acc[i][j][2]) |
               ((unsigned)f2bf(acc[i][j][3]) << 16);
        *(uint2*)&vtb[(((size_t)b * HH + h) * HD + d) * SS + s0] = pk;
      }
  }
}

// ---------------------------------------------------------------------------
// Output projection, bf16 inputs, fp32 output (coalesced), dbuf staging.
// ---------------------------------------------------------------------------
__global__ __launch_bounds__(256) void gemm_out_b(
    const unsigned short* __restrict__ A, const unsigned short* __restrict__ W,
    float* __restrict__ dst) {
  __shared__ unsigned short As[2][128 * 64];
  __shared__ unsigned short Bs[2][128 * 64];
  int tid = threadIdx.x;
  int m0 = blockIdx.x * 128;
  int n0 = blockIdx.y * 128;
  int lane = tid & 63;
  int w = tid >> 6;
  int wm = (w >> 1) * 64;
  int wn = (w & 1) * 64;

  float4_t acc[4][4];
#pragma unroll
  for (int i = 0; i < 4; i++)
#pragma unroll
    for (int j = 0; j < 4; j++)
#pragma unroll
      for (int r = 0; r < 4; r++) acc[i][j][r] = 0.f;

  STAGE_TILE(0, A, W, m0, n0, 0)
  int p = 0;
  for (int kt = 0; kt < DD; kt += 64) {
    __syncthreads();
    if (kt + 64 < DD) STAGE_TILE(p ^ 1, A, W, m0, n0, kt + 64)
#pragma unroll
    for (int kk = 0; kk < 64; kk += 32) {
      LOAD_FRAGS(p, kk)
#pragma unroll
      for (int i = 0; i < 4; i++)
#pragma unroll
        for (int j = 0; j < 4; j++)
          acc[i][j] = __builtin_amdgcn_mfma_f32_16x16x32_bf16(
              af[i], bfr[j], acc[i][j], 0, 0, 0);
    }
    p ^= 1;
  }

  int cn = lane & 15;
  int rb = (lane >> 4) * 4;
#pragma unroll
  for (int i = 0; i < 4; i++)
#pragma unroll
    for (int j = 0; j < 4; j++)
#pragma unroll
      for (int r = 0; r < 4; r++) {
        int m = m0 + wm + i * 16 + rb + r;
        int n = n0 + wn + j * 16 + cn;
        dst[(size_t)m * DD + n] = acc[i][j][r];
      }
}

// ---------------------------------------------------------------------------
// Block-sparse attention, fixed-max softmax, dbuf K/V LDS, 1 barrier/iter.
// Heavy blocks (l=0,63) split 8 ways -> partial O + rowsum to scratch.
// Grid: ids 0..383 heavy chunks, 384..1871 lights.
// ---------------------------------------------------------------------------
__global__ __launch_bounds__(256) void attn2(
    const unsigned short* __restrict__ q, const unsigned short* __restrict__ k,
    const unsigned short* __restrict__ vt, const int* __restrict__ graph,
    unsigned short* __restrict__ ctxb, float* __restrict__ part) {
  __shared__ unsigned short Ks[2][64 * LDK];   // K[key][d]
  __shared__ unsigned short Vs[2][64 * LDK];   // V^T[d][key]
  __shared__ unsigned short Ps[4][16 * LDK];   // per-wave P[q][key]

  int tid = threadIdx.x;
  int id = blockIdx.x;
  int b, h, l, nkb, heavy, chunk = 0, hid = 0;
  int list[8];
  if (id < 384) {
    heavy = 1;
    hid = id >> 3;
    chunk = id & 7;
    b = hid / 24;
    int r = hid % 24;
    h = r >> 1;
    l = (r & 1) ? (NBK - 1) : 0;
    nkb = 8;
#pragma unroll
    for (int i = 0; i < 8; i++) list[i] = chunk * 8 + i;
  } else {
    heavy = 0;
    int j = id - 384;
    b = j / 744;  // 744 = 12*62
    int r = j % 744;
    h = r / 62;
    l = 1 + r % 62;
    const int* g = graph + (((size_t)b * HH + h) * NBK + l) * MC;
    int n = 0;
    if (l == 1) {
      list[0] = 0; list[1] = 1; list[2] = 2; list[3] = NBK - 1; n = 4;
    } else if (l == NBK - 2) {
      list[0] = 0; list[1] = NBK - 3; list[2] = NBK - 2; list[3] = NBK - 1; n = 4;
    } else {
      list[0] = 0; list[1] = l - 1; list[2] = l; list[3] = l + 1;
      list[4] = NBK - 1; n = 5;
    }
    for (int m = 0; m < MC; m++) list[n++] = g[m];
    nkb = n;
  }
  size_t base = ((size_t)b * HH + h) * SS * HD;

  int lane = tid & 63;
  int w = tid >> 6;
  int lr = lane & 15;     // fragment m/n index
  int quad = lane >> 4;   // fragment k-group

  // Q fragments (A-layout) straight from global into registers (q pre-scaled).
  short8_t qa[2];
  {
    const unsigned short* qp =
        q + base + (size_t)(l * 64 + w * 16 + lr) * HD + quad * 8;
    qa[0] = *(const short8_t*)qp;
    qa[1] = *(const short8_t*)(qp + 32);
  }

  float4_t Ot[4];
  float ls[4];  // per-lane partial row sums (4 cols/row this lane)
#pragma unroll
  for (int t = 0; t < 4; t++)
#pragma unroll
    for (int r = 0; r < 4; r++) Ot[t][r] = 0.f;
#pragma unroll
  for (int r = 0; r < 4; r++) ls[r] = 0.f;

  // staging: each thread moves 2x16B for K and 2x16B for Vt
  int srow = tid >> 3;          // 0..31
  int scol = (tid & 7) * 8;     // 0..56

  uint4 kr0, kr1, vr0, vr1;
  {
    int kb = list[0];
    const unsigned short* kp = k + base + (size_t)(kb * 64 + srow) * HD + scol;
    const unsigned short* vp = vt + base + (size_t)srow * SS + kb * 64 + scol;
    kr0 = *(const uint4*)kp;
    kr1 = *(const uint4*)(kp + 32 * HD);
    vr0 = *(const uint4*)vp;
    vr1 = *(const uint4*)(vp + 32 * SS);
  }
  // write block 0 into buf 0
  *(uint4*)&Ks[0][srow * LDK + scol] = kr0;
  *(uint4*)&Ks[0][(srow + 32) * LDK + scol] = kr1;
  *(uint4*)&Vs[0][srow * LDK + scol] = vr0;
  *(uint4*)&Vs[0][(srow + 32) * LDK + scol] = vr1;
  int p = 0;

  for (int t = 0; t < nkb; t++) {
    __syncthreads();  // buf[p] writes visible; all waves done reading buf[p^1]

    if (t + 1 < nkb) {  // issue next block's global loads (fly during compute)
      int kb = list[t + 1];
      const unsigned short* kp = k + base + (size_t)(kb * 64 + srow) * HD + scol;
      const unsigned short* vp = vt + base + (size_t)srow * SS + kb * 64 + scol;
      kr0 = *(const uint4*)kp;
      kr1 = *(const uint4*)(kp + 32 * HD);
      vr0 = *(const uint4*)vp;
      vr1 = *(const uint4*)(vp + 32 * SS);
    }

    // S = Q K^T
    float4_t st[4];
#pragma unroll
    for (int tt = 0; tt < 4; tt++) {
#pragma unroll
      for (int r = 0; r < 4; r++) st[tt][r] = 0.f;
      short8_t kb0 = *(const short8_t*)&Ks[p][(tt * 16 + lr) * LDK + quad * 8];
      short8_t kb1 =
          *(const short8_t*)&Ks[p][(tt * 16 + lr) * LDK + quad * 8 + 32];
      st[tt] = __builtin_amdgcn_mfma_f32_16x16x32_bf16(qa[0], kb0, st[tt], 0, 0, 0);
      st[tt] = __builtin_amdgcn_mfma_f32_16x16x32_bf16(qa[1], kb1, st[tt], 0, 0, 0);
    }

    // fixed-max softmax: p = exp(s); per-lane partial sums, no shuffles.
#pragma unroll
    for (int tt = 0; tt < 4; tt++)
#pragma unroll
      for (int r = 0; r < 4; r++) {
        float pv = __expf(st[tt][r]);
        st[tt][r] = pv;
        ls[r] += pv;
        Ps[w][(quad * 4 + r) * LDK + tt * 16 + lr] = f2bf(pv);
      }

    // O += P V
#pragma unroll
    for (int s = 0; s < 2; s++) {
      short8_t pa = *(const short8_t*)&Ps[w][lr * LDK + s * 32 + quad * 8];
#pragma unroll
      for (int tt = 0; tt < 4; tt++) {
        short8_t vb =
            *(const short8_t*)&Vs[p][(tt * 16 + lr) * LDK + s * 32 + quad * 8];
        Ot[tt] = __builtin_amdgcn_mfma_f32_16x16x32_bf16(pa, vb, Ot[tt], 0, 0, 0);
      }
    }

    if (t + 1 < nkb) {  // write prefetched regs into the other buffer
      *(uint4*)&Ks[p ^ 1][srow * LDK + scol] = kr0;
      *(uint4*)&Ks[p ^ 1][(srow + 32) * LDK + scol] = kr1;
      *(uint4*)&Vs[p ^ 1][srow * LDK + scol] = vr0;
      *(uint4*)&Vs[p ^ 1][(srow + 32) * LDK + scol] = vr1;
    }
    p ^= 1;
  }

  // reduce row sums across the 16 lanes holding each row
#pragma unroll
  for (int r = 0; r < 4; r++)
#pragma unroll
    for (int off = 1; off < 16; off <<= 1) ls[r] += __shfl_xor(ls[r], off);

  if (!heavy) {
#pragma unroll
    for (int r = 0; r < 4; r++) {
      float inv = 1.f / ls[r];
      size_t row = (size_t)b * SS + (size_t)l * 64 + w * 16 + quad * 4 + r;
#pragma unroll
      for (int tt = 0; tt < 4; tt++)
        ctxb[row * DD + h * HD + tt * 16 + lr] = f2bf(Ot[tt][r] * inv);
    }
  } else {
    float* pb = part + ((size_t)hid * 8 + chunk) * 4160;  // 64*64 O + 64 lsum
#pragma unroll
    for (int r = 0; r < 4; r++) {
      int rowi = w * 16 + quad * 4 + r;
#pragma unroll
      for (int tt = 0; tt < 4; tt++)
        pb[rowi * 64 + tt * 16 + lr] = Ot[tt][r];
      if (lr == 0) pb[4096 + rowi] = ls[r];
    }
  }
}

// ---------------------------------------------------------------------------
// Combine the 8 partials of each heavy block, normalize, write bf16 ctx.
// ---------------------------------------------------------------------------
__global__ __launch_bounds__(256) void reduce_heavy(
    const float* __restrict__ part, unsigned short* __restrict__ ctxb) {
  __shared__ float lrow[64];
  int hid = blockIdx.x;
  int tid = threadIdx.x;
  int b = hid / 24;
  int r = hid % 24;
  int h = r >> 1;
  int l = (r & 1) ? (NBK - 1) : 0;
  const float* pb = part + (size_t)hid * 8 * 4160;
  if (tid < 64) {
    float s = 0.f;
#pragma unroll
    for (int c = 0; c < 8; c++) s += pb[c * 4160 + 4096 + tid];
    lrow[tid] = s;
  }
  __syncthreads();
#pragma unroll
  for (int e = tid; e < 4096; e += 256) {
    float o = 0.f;
#pragma unroll
    for (int c = 0; c < 8; c++) o += pb[c * 4160 + e];
    int rowi = e >> 6, col = e & 63;
    size_t row = (size_t)b * SS + (size_t)l * 64 + rowi;
    ctxb[row * DD + h * HD + col] = f2bf(o / lrow[rowi]);
  }
}

extern "C" void kernel_launch(void* const* d_in, const int* in_sizes, int n_in,
                              void* d_out, int out_size, void* d_ws,
                              size_t ws_size, hipStream_t stream) {
  const float* hs = (const float*)d_in[0];
  const float* Wq = (const float*)d_in[1];
  const float* Wk = (const float*)d_in[2];
  const float* Wv = (const float*)d_in[3];
  const float* Wo = (const float*)d_in[4];
  const int* graph = (const int*)d_in[10];

  const size_t NHS = (size_t)BB * SS * DD;  // 6291456
  unsigned short* hsb = (unsigned short*)d_ws;
  unsigned short* wqkvb = hsb + NHS;            // 3*768*768
  unsigned short* wob = wqkvb + 3 * 768 * 768;  // 768*768
  unsigned short* qb = wob + 768 * 768;
  unsigned short* kb = qb + NHS;
  unsigned short* vtb = kb + NHS;
  unsigned short* ctxb = vtb + NHS;
  float* part = (float*)(ctxb + NHS);  // 48*8*4160 floats

  cvt_all<<<8448, 256, 0, stream>>>(hs, Wq, Wk, Wv, Wo, hsb, wqkvb, wob);
  gemm_qkv_b<<<dim3(64, 18, 1), 256, 0, stream>>>(hsb, wqkvb, qb, kb, vtb);
  attn2<<<1872, 256, 0, stream>>>(qb, kb, vtb, graph, ctxb, part);
  reduce_heavy<<<48, 256, 0, stream>>>(part, ctxb);
  gemm_out_b<<<dim3(64, 6, 1), 256, 0, stream>>>(ctxb, wob, (float*)d_out);
}